// Round 6
// baseline (223.071 us; speedup 1.0000x reference)
//
#include <hip/hip_runtime.h>
#include <hip/hip_bf16.h>

typedef __attribute__((ext_vector_type(8))) short short8;
typedef __attribute__((ext_vector_type(4))) float f32x4;

#define NNODES 8192
#define FDIM 128

// ---------------- helpers ----------------
static __device__ inline unsigned short f2bf(float f) {
    union { float f; unsigned int u; } a; a.f = f;
    unsigned int u = a.u;
    unsigned int r = u + 0x7FFFu + ((u >> 16) & 1u);
    return (unsigned short)(r >> 16);
}

static __device__ inline float bf2f(unsigned short u) {
    union { unsigned int u; float f; } c; c.u = ((unsigned int)u) << 16; return c.f;
}

// ---------------- zero ints ----------------
__global__ void k_zero(int* __restrict__ p, int n) {
    int i = blockIdx.x * blockDim.x + threadIdx.x;
    if (i < n) p[i] = 0;
}

// ---------------- int degree count ----------------
__global__ void k_deg_int(const int* __restrict__ src, const int* __restrict__ dst,
                          int* __restrict__ cnt_s, int* __restrict__ cnt_d, int E) {
    int e = blockIdx.x * blockDim.x + threadIdx.x;
    if (e < E) {
        atomicAdd(&cnt_s[src[e]], 1);
        atomicAdd(&cnt_d[dst[e]], 1);
    }
}

// ---------------- single-block: norm_s + exclusive scan over cnt_d ----------------
__global__ __launch_bounds__(256) void k_scan_norms(const int* __restrict__ cnt_s,
                                                    const int* __restrict__ cnt_d,
                                                    float* __restrict__ norm_s,
                                                    int* __restrict__ row_start,
                                                    int* __restrict__ cursor, int n) {
    __shared__ int partial[256];
    __shared__ int offs[257];
    int t = threadIdx.x;
    int base = t * 32;
#pragma unroll
    for (int i = 0; i < 32; ++i)
        norm_s[base + i] = rsqrtf(fmaxf((float)cnt_s[base + i], 1.0f));
    int local[32];
    int s = 0;
#pragma unroll
    for (int i = 0; i < 32; ++i) { local[i] = s; s += cnt_d[base + i]; }
    partial[t] = s;
    __syncthreads();
    if (t == 0) {
        int acc = 0;
        for (int i = 0; i < 256; ++i) { offs[i] = acc; acc += partial[i]; }
        offs[256] = acc;
    }
    __syncthreads();
    int o = offs[t];
#pragma unroll
    for (int i = 0; i < 32; ++i) {
        int v = o + local[i];
        row_start[base + i] = v;
        cursor[base + i] = v;
    }
    if (t == 0) row_start[n] = offs[256];
}

__global__ void k_fill(const int* __restrict__ src, const int* __restrict__ dst,
                       int* __restrict__ cursor, int* __restrict__ csr_src, int E) {
    int e = blockIdx.x * blockDim.x + threadIdx.x;
    if (e < E) {
        int pos = atomicAdd(&cursor[dst[e]], 1);
        csr_src[pos] = src[e];
    }
}

// ---------------- linear: Y[row] = bf16( (X[row] @ W) * norm[row] ) ----------------
// 256 threads, 16 rows/block; X-tile in LDS; group g: rows {2g,2g+1}, lane: 4 cols.
template<int K>
__global__ __launch_bounds__(256) void k_linear(const float* __restrict__ X,
                                                const float* __restrict__ W,
                                                const float* __restrict__ norm,
                                                unsigned short* __restrict__ Y) {
    __shared__ float xs[16][K];
    int t = threadIdx.x;
    int row0 = blockIdx.x * 16;
    constexpr int K4 = K / 4;
    constexpr int NCH = 16 * K4 / 256;
#pragma unroll
    for (int i = 0; i < NCH; ++i) {
        int c = t + i * 256;
        int r = c / K4, k4 = c % K4;
        *(float4*)&xs[r][k4 * 4] = *(const float4*)(X + (size_t)(row0 + r) * K + k4 * 4);
    }
    __syncthreads();

    int lane = t & 31, g = t >> 5;
    int r0 = g * 2, r1 = g * 2 + 1;
    int c = lane * 4;
    f32x4 acc0 = {0.f, 0.f, 0.f, 0.f}, acc1 = {0.f, 0.f, 0.f, 0.f};
    for (int k = 0; k < K; k += 4) {
        f32x4 x0 = *(f32x4*)&xs[r0][k];
        f32x4 x1 = *(f32x4*)&xs[r1][k];
#pragma unroll
        for (int kk = 0; kk < 4; ++kk) {
            f32x4 w = *(const f32x4*)(W + (size_t)(k + kk) * FDIM + c);
            acc0 += w * x0[kk];
            acc1 += w * x1[kk];
        }
    }
    float n0 = norm[row0 + r0], n1 = norm[row0 + r1];
    acc0 *= n0; acc1 *= n1;
    ushort4 u0, u1;
    u0.x = f2bf(acc0[0]); u0.y = f2bf(acc0[1]); u0.z = f2bf(acc0[2]); u0.w = f2bf(acc0[3]);
    u1.x = f2bf(acc1[0]); u1.y = f2bf(acc1[1]); u1.z = f2bf(acc1[2]); u1.w = f2bf(acc1[3]);
    *(ushort4*)(Y + (size_t)(row0 + r0) * FDIM + c) = u0;
    *(ushort4*)(Y + (size_t)(row0 + r1) * FDIM + c) = u1;
}

// ---------------- gather-aggregate + finalize ----------------
// 16 lanes per node (8 bf16 cols per lane, one 16B load/edge), 16 nodes/block.
// out = act( (sum_e Ybf[csr_src[e]]) * rsqrt(deg) + bias )
template<int MODE>  // 0: relu -> f32 out; 1: identity -> bf16 out
__global__ __launch_bounds__(256) void k_gather_agg(const unsigned short* __restrict__ Y,
                                                    const int* __restrict__ row_start,
                                                    const int* __restrict__ csr_src,
                                                    const float* __restrict__ bias,
                                                    void* __restrict__ outp) {
    int t = threadIdx.x;
    int node = blockIdx.x * 16 + (t >> 4);
    int c8 = (t & 15) << 3;  // column base, 0..120 step 8
    int beg = row_start[node], end = row_start[node + 1];
    f32x4 a0 = {0.f, 0.f, 0.f, 0.f}, a1 = {0.f, 0.f, 0.f, 0.f};
    f32x4 b0 = {0.f, 0.f, 0.f, 0.f}, b1 = {0.f, 0.f, 0.f, 0.f};
    int e = beg;
    for (; e + 1 < end; e += 2) {
        int s0 = csr_src[e], s1 = csr_src[e + 1];
        short8 v0 = *(const short8*)(Y + ((size_t)s0 << 7) + c8);
        short8 v1 = *(const short8*)(Y + ((size_t)s1 << 7) + c8);
#pragma unroll
        for (int i = 0; i < 4; ++i) {
            a0[i] += bf2f((unsigned short)v0[i]);
            a1[i] += bf2f((unsigned short)v0[i + 4]);
            b0[i] += bf2f((unsigned short)v1[i]);
            b1[i] += bf2f((unsigned short)v1[i + 4]);
        }
    }
    if (e < end) {
        int s0 = csr_src[e];
        short8 v0 = *(const short8*)(Y + ((size_t)s0 << 7) + c8);
#pragma unroll
        for (int i = 0; i < 4; ++i) {
            a0[i] += bf2f((unsigned short)v0[i]);
            a1[i] += bf2f((unsigned short)v0[i + 4]);
        }
    }
    a0 += b0; a1 += b1;
    float scale = rsqrtf(fmaxf((float)(end - beg), 1.0f));
    f32x4 bb0 = *(const f32x4*)(bias + c8);
    f32x4 bb1 = *(const f32x4*)(bias + c8 + 4);
    f32x4 v0 = a0 * scale + bb0;
    f32x4 v1 = a1 * scale + bb1;
    if (MODE == 0) {
#pragma unroll
        for (int i = 0; i < 4; ++i) { v0[i] = fmaxf(v0[i], 0.f); v1[i] = fmaxf(v1[i], 0.f); }
        float* o = (float*)outp + ((size_t)node << 7) + c8;
        *(f32x4*)o = v0;
        *(f32x4*)(o + 4) = v1;
    } else {
        short8 u;
#pragma unroll
        for (int i = 0; i < 4; ++i) {
            u[i] = (short)f2bf(v0[i]);
            u[i + 4] = (short)f2bf(v1[i]);
        }
        *(short8*)((unsigned short*)outp + ((size_t)node << 7) + c8) = u;
    }
}

// ---------------- decode: C = sigmoid(H @ H^T), H is [8192][128] bf16 ----------------
// 128x128 tile/block, 4 waves, mfma_f32_16x16x32_bf16, XOR-swizzled LDS,
// nontemporal dword stores (64B segments), rcp-based sigmoid.
__global__ __launch_bounds__(256) void k_decode(const __hip_bfloat16* __restrict__ H,
                                                float* __restrict__ C) {
    __shared__ __align__(16) unsigned char smem[65536];
    unsigned char* sA = smem;
    unsigned char* sB = smem + 32768;
    const int ti = blockIdx.x, tj = blockIdx.y;
    const int t = threadIdx.x;
    const unsigned char* gH = (const unsigned char*)H;

#pragma unroll
    for (int i = 0; i < 8; ++i) {
        int chunk = t + i * 256;
        int row = chunk >> 4;
        int cc = (chunk & 15) << 4;
        int lofs = row * 256 + (cc ^ ((row & 7) << 4));
        *(float4*)(sA + lofs) = *(const float4*)(gH + ((size_t)(ti * 128 + row) << 8) + cc);
        *(float4*)(sB + lofs) = *(const float4*)(gH + ((size_t)(tj * 128 + row) << 8) + cc);
    }
    __syncthreads();

    const int w = t >> 6, lane = t & 63;
    const int wr = (w >> 1) * 64, wc = (w & 1) * 64;
    const int lr = lane & 15;
    const int lk = (lane >> 4) * 16;

    f32x4 acc[4][4] = {};

#pragma unroll
    for (int ks = 0; ks < 4; ++ks) {
        short8 af[4], bfr[4];
#pragma unroll
        for (int mi = 0; mi < 4; ++mi) {
            int row = wr + mi * 16 + lr;
            int off = row * 256 + ((ks * 64 + lk) ^ ((row & 7) << 4));
            af[mi] = *(const short8*)(sA + off);
        }
#pragma unroll
        for (int ni = 0; ni < 4; ++ni) {
            int row = wc + ni * 16 + lr;
            int off = row * 256 + ((ks * 64 + lk) ^ ((row & 7) << 4));
            bfr[ni] = *(const short8*)(sB + off);
        }
#pragma unroll
        for (int mi = 0; mi < 4; ++mi)
#pragma unroll
            for (int ni = 0; ni < 4; ++ni)
                acc[mi][ni] = __builtin_amdgcn_mfma_f32_16x16x32_bf16(af[mi], bfr[ni],
                                                                      acc[mi][ni], 0, 0, 0);
    }

    // C/D layout: col=lane&15, row=(lane>>4)*4+r (m89); sigmoid via v_exp + v_rcp
    const int rbase = (lane >> 4) * 4;
    const int cbase = lane & 15;
#pragma unroll
    for (int mi = 0; mi < 4; ++mi) {
        int rowb = ti * 128 + wr + mi * 16 + rbase;
#pragma unroll
        for (int ni = 0; ni < 4; ++ni) {
            int col = tj * 128 + wc + ni * 16 + cbase;
#pragma unroll
            for (int r = 0; r < 4; ++r) {
                float s = __builtin_amdgcn_rcpf(1.0f + __expf(-acc[mi][ni][r]));
                __builtin_nontemporal_store(s, C + (size_t)(rowb + r) * NNODES + col);
            }
        }
    }
}

extern "C" void kernel_launch(void* const* d_in, const int* in_sizes, int n_in,
                              void* d_out, int out_size, void* d_ws, size_t ws_size,
                              hipStream_t stream) {
    const float* x  = (const float*)d_in[0];
    const int* src  = (const int*)d_in[1];
    const int* dst  = (const int*)d_in[2];
    const float* W1 = (const float*)d_in[3];
    const float* b1 = (const float*)d_in[4];
    const float* W2 = (const float*)d_in[5];
    const float* b2 = (const float*)d_in[6];
    float* out = (float*)d_out;
    const int E = in_sizes[1];

    char* ws = (char*)d_ws;
    float* norm_s    = (float*)(ws + 0);
    int*   cnt_s     = (int*)(ws + (64 << 10));    // cnt_s + cnt_d contiguous 64KB
    int*   cnt_d     = (int*)(ws + (96 << 10));
    int*   row_start = (int*)(ws + (128 << 10));   // 8193 ints
    int*   cursor    = (int*)(ws + (164 << 10));
    int*   csr_src   = (int*)(ws + (196 << 10));   // E ints = 1MB
    char*  big       = ws + (196 << 10) + ((size_t)E * 4);
    unsigned short* ybf  = (unsigned short*)big;            // 2MB bf16 messages
    float*          h1   = (float*)(big + (2 << 20));       // 4MB f32
    __hip_bfloat16* h2bf = (__hip_bfloat16*)(big + (6 << 20));  // 2MB

    // zero degree counters (kernel, not memset — in-graph fill nodes are slow)
    k_zero<<<(2 * NNODES + 255) / 256, 256, 0, stream>>>(cnt_s, 2 * NNODES);

    // degrees, norms, CSR (graph shared by both layers)
    k_deg_int<<<(E + 255) / 256, 256, 0, stream>>>(src, dst, cnt_s, cnt_d, E);
    k_scan_norms<<<1, 256, 0, stream>>>(cnt_s, cnt_d, norm_s, row_start, cursor, NNODES);
    k_fill<<<(E + 255) / 256, 256, 0, stream>>>(src, dst, cursor, csr_src, E);

    // layer 1: y1 = bf16((x@W1)*ns) ; h1 = relu(gather(y1)*nd + b1)  (f32)
    k_linear<256><<<NNODES / 16, 256, 0, stream>>>(x, W1, norm_s, ybf);
    k_gather_agg<0><<<NNODES / 16, 256, 0, stream>>>(ybf, row_start, csr_src, b1, h1);

    // layer 2: y2 = bf16((h1@W2)*ns) ; h2 = gather(y2)*nd + b2 -> bf16
    k_linear<128><<<NNODES / 16, 256, 0, stream>>>(h1, W2, norm_s, ybf);
    k_gather_agg<1><<<NNODES / 16, 256, 0, stream>>>(ybf, row_start, csr_src, b2, h2bf);

    // decode: out = sigmoid(h2 @ h2^T)
    k_decode<<<dim3(64, 64), 256, 0, stream>>>(h2bf, out);
}